// Round 1
// baseline (645.434 us; speedup 1.0000x reference)
//
#include <hip/hip_runtime.h>

#define N_NODES 100000
#define N_EDGES 3200000
#define IN_F    256
#define OUT_F   256
#define CLAMP_V 10.0f

__device__ __forceinline__ float clampf(float v) {
    return fminf(fmaxf(v, -CLAMP_V), CLAMP_V);
}

// ---------------------------------------------------------------------------
// Kernel 1: CSR row_ptr from sorted adj_rows via per-row lower_bound.
// row_ptr[r] = first edge index e with adj_rows[e] >= r, for r in [0, N].
// ---------------------------------------------------------------------------
__global__ __launch_bounds__(256) void build_row_ptr(
    const int* __restrict__ rows, int* __restrict__ row_ptr) {
    int r = blockIdx.x * blockDim.x + threadIdx.x;
    if (r > N_NODES) return;
    int lo = 0, hi = N_EDGES;
    while (lo < hi) {
        int mid = (lo + hi) >> 1;
        if (rows[mid] < r) lo = mid + 1; else hi = mid;
    }
    row_ptr[r] = lo;
}

// ---------------------------------------------------------------------------
// Kernel 2: support = clip(clip(x) @ W).  fp32 SGEMM, 64x64 tile, BK=32,
// 256 threads, 4x4 micro-tile per thread.
// ---------------------------------------------------------------------------
#define BM 64
#define BN 64
#define BK 32

__global__ __launch_bounds__(256) void gemm_support(
    const float* __restrict__ x, const float* __restrict__ w,
    float* __restrict__ support) {
    __shared__ float As[BK][BM + 4];   // [k][m], padded
    __shared__ float Bs[BK][BN + 4];   // [k][n], padded

    const int t  = threadIdx.x;
    const int tx = t & 15;             // 0..15 -> 4 cols each
    const int ty = t >> 4;             // 0..15 -> 4 rows each
    const int rowBase = blockIdx.x * BM;
    const int colBase = blockIdx.y * BN;

    float acc[4][4] = {};

    for (int k0 = 0; k0 < IN_F; k0 += BK) {
        // ---- stage A tile (64 rows x 32 k), transposed into As[k][m] ----
        #pragma unroll
        for (int l = 0; l < 2; ++l) {
            int f   = t + l * 256;       // 0..511 float4 slots
            int row = f >> 3;            // 0..63
            int kq  = f & 7;             // 0..7  (k = kq*4)
            int grow = rowBase + row;
            float4 v = make_float4(0.f, 0.f, 0.f, 0.f);
            if (grow < N_NODES)
                v = *(const float4*)(x + (size_t)grow * IN_F + k0 + kq * 4);
            v.x = clampf(v.x); v.y = clampf(v.y);
            v.z = clampf(v.z); v.w = clampf(v.w);
            As[kq * 4 + 0][row] = v.x;
            As[kq * 4 + 1][row] = v.y;
            As[kq * 4 + 2][row] = v.z;
            As[kq * 4 + 3][row] = v.w;
        }
        // ---- stage B tile (32 k x 64 n) into Bs[k][n] ----
        #pragma unroll
        for (int l = 0; l < 2; ++l) {
            int f  = t + l * 256;        // 0..511
            int k  = f >> 4;             // 0..31
            int nq = f & 15;             // 0..15
            float4 v = *(const float4*)(w + (size_t)(k0 + k) * OUT_F + colBase + nq * 4);
            *(float4*)&Bs[k][nq * 4] = v;
        }
        __syncthreads();

        #pragma unroll
        for (int k = 0; k < BK; ++k) {
            float4 a4 = *(const float4*)&As[k][ty * 4];
            float4 b4 = *(const float4*)&Bs[k][tx * 4];
            float a[4] = {a4.x, a4.y, a4.z, a4.w};
            float b[4] = {b4.x, b4.y, b4.z, b4.w};
            #pragma unroll
            for (int i = 0; i < 4; ++i)
                #pragma unroll
                for (int j = 0; j < 4; ++j)
                    acc[i][j] += a[i] * b[j];
        }
        __syncthreads();
    }

    // ---- store clip(support) ----
    #pragma unroll
    for (int i = 0; i < 4; ++i) {
        int grow = rowBase + ty * 4 + i;
        if (grow < N_NODES) {
            float4 o;
            o.x = clampf(acc[i][0]); o.y = clampf(acc[i][1]);
            o.z = clampf(acc[i][2]); o.w = clampf(acc[i][3]);
            *(float4*)(support + (size_t)grow * OUT_F + colBase + tx * 4) = o;
        }
    }
}

// ---------------------------------------------------------------------------
// Kernel 3: out[r] = clip(relu(clip(sum_e val*support[col]) + bias)).
// One wave per row; lane owns 4 features (float4). Unroll-by-4 over edges.
// ---------------------------------------------------------------------------
__global__ __launch_bounds__(256) void spmm_out(
    const float* __restrict__ support, const int* __restrict__ row_ptr,
    const int* __restrict__ cols, const float* __restrict__ vals,
    const float* __restrict__ bias, float* __restrict__ out) {
    const int wid  = threadIdx.x >> 6;
    const int lane = threadIdx.x & 63;
    const int row  = blockIdx.x * 4 + wid;
    if (row >= N_NODES) return;

    const int e0 = row_ptr[row];
    const int e1 = row_ptr[row + 1];

    const float4* sup4 = (const float4*)support;
    float4 acc = make_float4(0.f, 0.f, 0.f, 0.f);

    int e = e0;
    for (; e + 4 <= e1; e += 4) {
        int   c0 = cols[e],     c1 = cols[e + 1];
        int   c2 = cols[e + 2], c3 = cols[e + 3];
        float v0 = vals[e],     v1 = vals[e + 1];
        float v2 = vals[e + 2], v3 = vals[e + 3];
        float4 g0 = sup4[(size_t)c0 * 64 + lane];
        float4 g1 = sup4[(size_t)c1 * 64 + lane];
        float4 g2 = sup4[(size_t)c2 * 64 + lane];
        float4 g3 = sup4[(size_t)c3 * 64 + lane];
        acc.x += v0 * g0.x; acc.y += v0 * g0.y; acc.z += v0 * g0.z; acc.w += v0 * g0.w;
        acc.x += v1 * g1.x; acc.y += v1 * g1.y; acc.z += v1 * g1.z; acc.w += v1 * g1.w;
        acc.x += v2 * g2.x; acc.y += v2 * g2.y; acc.z += v2 * g2.z; acc.w += v2 * g2.w;
        acc.x += v3 * g3.x; acc.y += v3 * g3.y; acc.z += v3 * g3.z; acc.w += v3 * g3.w;
    }
    for (; e < e1; ++e) {
        int   c = cols[e];
        float v = vals[e];
        float4 g = sup4[(size_t)c * 64 + lane];
        acc.x += v * g.x; acc.y += v * g.y; acc.z += v * g.z; acc.w += v * g.w;
    }

    float4 b4 = ((const float4*)bias)[lane];
    float4 o;
    // clip(acc) + bias -> relu -> clip; post-relu value >= 0 so only the
    // upper clip binds afterwards.
    o.x = fminf(fmaxf(clampf(acc.x) + b4.x, 0.f), CLAMP_V);
    o.y = fminf(fmaxf(clampf(acc.y) + b4.y, 0.f), CLAMP_V);
    o.z = fminf(fmaxf(clampf(acc.z) + b4.z, 0.f), CLAMP_V);
    o.w = fminf(fmaxf(clampf(acc.w) + b4.w, 0.f), CLAMP_V);
    ((float4*)out)[(size_t)row * 64 + lane] = o;
}

// ---------------------------------------------------------------------------
extern "C" void kernel_launch(void* const* d_in, const int* in_sizes, int n_in,
                              void* d_out, int out_size, void* d_ws, size_t ws_size,
                              hipStream_t stream) {
    const float* x        = (const float*)d_in[0];
    const int*   adj_rows = (const int*)d_in[1];
    const int*   adj_cols = (const int*)d_in[2];
    const float* adj_vals = (const float*)d_in[3];
    const float* weight   = (const float*)d_in[4];
    const float* bias     = (const float*)d_in[5];
    float*       out      = (float*)d_out;

    // workspace layout: support [N*256 f32] then row_ptr [N+1 int]
    float* support = (float*)d_ws;
    int*   row_ptr = (int*)((char*)d_ws + (size_t)N_NODES * OUT_F * sizeof(float));

    // 1. CSR offsets (independent of GEMM; stream-ordered before SpMM)
    build_row_ptr<<<(N_NODES + 1 + 255) / 256, 256, 0, stream>>>(adj_rows, row_ptr);

    // 2. support = clip(clip(x) @ W)
    dim3 ggrid((N_NODES + BM - 1) / BM, OUT_F / BN);
    gemm_support<<<ggrid, 256, 0, stream>>>(x, weight, support);

    // 3. SpMM + epilogue
    spmm_out<<<(N_NODES + 3) / 4, 256, 0, stream>>>(support, row_ptr, adj_cols,
                                                    adj_vals, bias, out);
}

// Round 2
// 325.632 us; speedup vs baseline: 1.9821x; 1.9821x over previous
//
#include <hip/hip_runtime.h>

#define N_NODES 100000
#define N_EDGES 3200000
#define IN_F    256
#define OUT_F   256
#define CLAMP_V 10.0f

typedef __attribute__((ext_vector_type(8))) short bf16x8;
typedef __attribute__((ext_vector_type(4))) float f32x4;

__device__ __forceinline__ float clampf(float v) {
    return fminf(fmaxf(v, -CLAMP_V), CLAMP_V);
}
// RNE float -> bf16 (inputs are clamped/finite; no NaN handling needed)
__device__ __forceinline__ unsigned short f2bf(float f) {
    unsigned u = __float_as_uint(f);
    u += 0x7fffu + ((u >> 16) & 1u);
    return (unsigned short)(u >> 16);
}
__device__ __forceinline__ float bflo(unsigned w) { return __uint_as_float(w << 16); }
__device__ __forceinline__ float bfhi(unsigned w) { return __uint_as_float(w & 0xffff0000u); }

// ---------------------------------------------------------------------------
// Kernel 0: W (fp32 [K=256][N=256]) -> bf16, pre-swizzled for LDS B-frag reads.
// Element (k,n) stored at  n*256 + ((k>>3) ^ (n&7))*8 + (k&7).
// ---------------------------------------------------------------------------
__global__ __launch_bounds__(256) void convert_w(
    const float* __restrict__ w, unsigned short* __restrict__ wt) {
    int i = blockIdx.x * 256 + threadIdx.x;   // 65536 total
    int k = i & 255, n = i >> 8;
    float v = w[(size_t)k * OUT_F + n];
    int dst = n * 256 + (((k >> 3) ^ (n & 7)) << 3) + (k & 7);
    wt[dst] = f2bf(v);
}

// ---------------------------------------------------------------------------
// Kernel 1: CSR row_ptr from sorted adj_rows (binary search per row).
// ---------------------------------------------------------------------------
__global__ __launch_bounds__(256) void build_row_ptr(
    const int* __restrict__ rows, int* __restrict__ row_ptr) {
    int r = blockIdx.x * blockDim.x + threadIdx.x;
    if (r > N_NODES) return;
    int lo = 0, hi = N_EDGES;
    while (lo < hi) {
        int mid = (lo + hi) >> 1;
        if (rows[mid] < r) lo = mid + 1; else hi = mid;
    }
    row_ptr[r] = lo;
}

// ---------------------------------------------------------------------------
// Kernel 2: support(bf16) = clip(clip(x) @ W)  via mfma_f32_16x16x32_bf16.
// Block: 4 waves, tile 64 rows x 256 cols (full N). W fully in LDS (128KB,
// pre-swizzled). A: 64x32 fp32 per K-step -> clamp -> bf16 -> LDS, 1-deep
// register prefetch. Wave w owns cols [w*64, w*64+64): 4x4 fragment grid.
// ---------------------------------------------------------------------------
__global__ __launch_bounds__(256) void gemm_mfma(
    const float* __restrict__ x, const unsigned short* __restrict__ wt,
    unsigned short* __restrict__ support) {
    __shared__ uint4 wlds[8192];    // 128 KB: [n][chunk^(n&7)] 16B chunks
    __shared__ uint4 As2[4][64];    // 4 KB: [k-chunk][row] 16B chunks

    const int t    = threadIdx.x;
    const int lane = t & 63;
    const int w    = t >> 6;        // wave id 0..3
    const int l15  = lane & 15;
    const int l4   = lane >> 4;     // k-chunk group 0..3
    const int rowBase = blockIdx.x * 64;

    // ---- W -> LDS (linear copy; swizzle was pre-applied in global) ----
    {
        const uint4* g = (const uint4*)wt;
        #pragma unroll
        for (int i = 0; i < 32; ++i)
            wlds[i * 256 + t] = g[i * 256 + t];
    }

    // ---- A staging: thread handles row=lane, k-chunk=w (8 floats/step) ----
    const int  arow = rowBase + lane;
    const bool vld  = arow < N_NODES;
    const float* xp = x + (size_t)arow * IN_F + w * 8;

    float4 c0 = make_float4(0.f,0.f,0.f,0.f), c1 = c0, n0 = c0, n1 = c0;
    if (vld) { c0 = *(const float4*)(xp); c1 = *(const float4*)(xp + 4); }

    f32x4 acc[4][4];
    #pragma unroll
    for (int m = 0; m < 4; ++m)
        #pragma unroll
        for (int n = 0; n < 4; ++n)
            acc[m][n] = (f32x4)0.f;

    for (int s = 0; s < 8; ++s) {
        __syncthreads();   // prev-step frag reads done (and W-load on s=0)
        uint4 p;
        p.x = (unsigned)f2bf(clampf(c0.x)) | ((unsigned)f2bf(clampf(c0.y)) << 16);
        p.y = (unsigned)f2bf(clampf(c0.z)) | ((unsigned)f2bf(clampf(c0.w)) << 16);
        p.z = (unsigned)f2bf(clampf(c1.x)) | ((unsigned)f2bf(clampf(c1.y)) << 16);
        p.w = (unsigned)f2bf(clampf(c1.z)) | ((unsigned)f2bf(clampf(c1.w)) << 16);
        As2[w][lane] = p;
        if (s < 7 && vld) {            // prefetch next K-step into regs
            const float* xn = xp + (s + 1) * 32;
            n0 = *(const float4*)(xn);
            n1 = *(const float4*)(xn + 4);
        }
        __syncthreads();   // As2 ready

        bf16x8 a[4], b[4];
        #pragma unroll
        for (int m = 0; m < 4; ++m)
            a[m] = *(const bf16x8*)&As2[l4][m * 16 + l15];
        #pragma unroll
        for (int n = 0; n < 4; ++n) {
            int ncol  = w * 64 + n * 16 + l15;
            int chunk = ncol * 32 + ((s * 4 + l4) ^ (ncol & 7));
            b[n] = *(const bf16x8*)&wlds[chunk];
        }
        #pragma unroll
        for (int m = 0; m < 4; ++m)
            #pragma unroll
            for (int n = 0; n < 4; ++n)
                acc[m][n] = __builtin_amdgcn_mfma_f32_16x16x32_bf16(
                    a[m], b[n], acc[m][n], 0, 0, 0);

        c0 = n0; c1 = n1;
    }

    // ---- store clip(support) as bf16 [N][256] row-major ----
    #pragma unroll
    for (int m = 0; m < 4; ++m) {
        int grow = rowBase + m * 16 + l4 * 4;
        #pragma unroll
        for (int r = 0; r < 4; ++r) {
            if (grow + r < N_NODES) {
                size_t base = (size_t)(grow + r) * OUT_F + w * 64 + l15;
                #pragma unroll
                for (int n = 0; n < 4; ++n)
                    support[base + n * 16] = f2bf(clampf(acc[m][n][r]));
            }
        }
    }
}

// ---------------------------------------------------------------------------
// Kernel 3: out[r] = clip(relu(clip(sum val*support[c]) + bias)).
// One wave per row, TWO edges in flight per wave: lanes 0-31 even edge,
// lanes 32-63 odd edge; each lane gathers 16B (8 bf16 features). Halves
// combined via shfl_xor(32) at the end. fp32 accumulate.
// ---------------------------------------------------------------------------
__global__ __launch_bounds__(256) void spmm_out(
    const unsigned short* __restrict__ support, const int* __restrict__ row_ptr,
    const int* __restrict__ cols, const float* __restrict__ vals,
    const float* __restrict__ bias, float* __restrict__ out) {
    const int wid  = threadIdx.x >> 6;
    const int lane = threadIdx.x & 63;
    const int row  = blockIdx.x * 4 + wid;
    if (row >= N_NODES) return;

    const int e0   = row_ptr[row];
    const int e1   = row_ptr[row + 1];
    const int half = lane >> 5;       // 0: even edge, 1: odd edge
    const int c32  = lane & 31;       // 16B chunk within support row

    const uint4* sup4 = (const uint4*)support;   // 32 chunks per node
    float acc[8] = {0.f,0.f,0.f,0.f,0.f,0.f,0.f,0.f};

    int e = e0;
    for (; e + 4 <= e1; e += 4) {     // 4 edges per iter (2 pair-steps)
        int   ea = e + half, eb = ea + 2;
        int   ca = cols[ea], cb = cols[eb];
        float va = vals[ea], vb = vals[eb];
        uint4 ga = sup4[(size_t)ca * 32 + c32];
        uint4 gb = sup4[(size_t)cb * 32 + c32];
        acc[0] += va * bflo(ga.x); acc[1] += va * bfhi(ga.x);
        acc[2] += va * bflo(ga.y); acc[3] += va * bfhi(ga.y);
        acc[4] += va * bflo(ga.z); acc[5] += va * bfhi(ga.z);
        acc[6] += va * bflo(ga.w); acc[7] += va * bfhi(ga.w);
        acc[0] += vb * bflo(gb.x); acc[1] += vb * bfhi(gb.x);
        acc[2] += vb * bflo(gb.y); acc[3] += vb * bfhi(gb.y);
        acc[4] += vb * bflo(gb.z); acc[5] += vb * bfhi(gb.z);
        acc[6] += vb * bflo(gb.w); acc[7] += vb * bfhi(gb.w);
    }
    for (; e < e1; e += 2) {          // tail: 1-2 edges, mask odd half
        int   ea = e + half;
        bool  ok = ea < e1;
        int   ca = cols[ok ? ea : e];
        float va = ok ? vals[ea] : 0.f;
        uint4 ga = sup4[(size_t)ca * 32 + c32];
        acc[0] += va * bflo(ga.x); acc[1] += va * bfhi(ga.x);
        acc[2] += va * bflo(ga.y); acc[3] += va * bfhi(ga.y);
        acc[4] += va * bflo(ga.z); acc[5] += va * bfhi(ga.z);
        acc[6] += va * bflo(ga.w); acc[7] += va * bfhi(ga.w);
    }

    #pragma unroll
    for (int j = 0; j < 8; ++j)
        acc[j] += __shfl_xor(acc[j], 32);

    // epilogue: clip -> +bias -> relu -> clip. Lane writes 4 features:
    // half 0 -> features c32*8+0..3, half 1 -> c32*8+4..7.
    const float4 b4 = ((const float4*)bias)[c32 * 2 + half];
    float4 o;
    o.x = fminf(fmaxf(clampf(acc[half * 4 + 0]) + b4.x, 0.f), CLAMP_V);
    o.y = fminf(fmaxf(clampf(acc[half * 4 + 1]) + b4.y, 0.f), CLAMP_V);
    o.z = fminf(fmaxf(clampf(acc[half * 4 + 2]) + b4.z, 0.f), CLAMP_V);
    o.w = fminf(fmaxf(clampf(acc[half * 4 + 3]) + b4.w, 0.f), CLAMP_V);
    *(float4*)(out + (size_t)row * OUT_F + c32 * 8 + half * 4) = o;
}

// ---------------------------------------------------------------------------
extern "C" void kernel_launch(void* const* d_in, const int* in_sizes, int n_in,
                              void* d_out, int out_size, void* d_ws, size_t ws_size,
                              hipStream_t stream) {
    const float* x        = (const float*)d_in[0];
    const int*   adj_rows = (const int*)d_in[1];
    const int*   adj_cols = (const int*)d_in[2];
    const float* adj_vals = (const float*)d_in[3];
    const float* weight   = (const float*)d_in[4];
    const float* bias     = (const float*)d_in[5];
    float*       out      = (float*)d_out;

    // workspace: support bf16 [100000][256] | row_ptr [N+1] | wt bf16 swizzled
    char* ws = (char*)d_ws;
    unsigned short* support = (unsigned short*)ws;                   // 51,200,000 B
    int*            row_ptr = (int*)(ws + 51200000);                 //    400,004 B
    unsigned short* wt      = (unsigned short*)(ws + 51600064);      //    131,072 B

    convert_w<<<256, 256, 0, stream>>>(weight, wt);
    build_row_ptr<<<(N_NODES + 1 + 255) / 256, 256, 0, stream>>>(adj_rows, row_ptr);
    gemm_mfma<<<(N_NODES + 63) / 64, 256, 0, stream>>>(x, wt, support);
    spmm_out<<<(N_NODES + 3) / 4, 256, 0, stream>>>(support, row_ptr, adj_cols,
                                                    adj_vals, bias, out);
}